// Round 1
// 167.860 us; speedup vs baseline: 1.2743x; 1.2743x over previous
//
#include <hip/hip_runtime.h>

#define LRELU_ALPHA 0.2f
#define NEG_INF_V  -9.0e15f

// Round-9: phase2 rewritten on the matrix pipe. Split-bf16 (hi+lo, 3-product)
// MFMA 16x16x32 for att@Wh: fp32-class precision, 19.3 GFLOP-equiv on a
// ~2 PF pipe instead of 6.4 GFLOP on the 157 TF fp32 vector pipe.
// - p generated directly in A-frag layout (lane=col,g; reg=r; j=k0+8g+r):
//   no score matrix, no LDS, no barriers in phase2.
// - B-frags (WhT hi/lo bf16, [bt][o][j]) read straight from global: the
//   16-col x 4-kquarter pattern covers 16 full 64B lines per instruction.
// - denominator via MFMA against a ones-frag: lands in D layout, same
//   weights as numerator -> quantization cancels in the ratio.
// - k-mapping consistency (same sigma for A and B) makes the layout robust;
//   only C/D layout (col=lane&15, row=(lane>>4)*4+reg) must be exact.
// phase1 keeps its FMA core; epilogue restages Wh chunk via hT (reuse) and
// emits WhT_hi/WhT_lo. Workspace layout size unchanged (25,985,792 B).

#define FMA4(d, s, v)                          \
    d.x = fmaf(s, v.x, d.x);                   \
    d.y = fmaf(s, v.y, d.y);                   \
    d.z = fmaf(s, v.z, d.z);                   \
    d.w = fmaf(s, v.w, d.w);

typedef __attribute__((ext_vector_type(8))) short short8;
typedef __attribute__((ext_vector_type(4))) float f32x4;

union U16x8 { uint4 v; short8 s; };

static __device__ __forceinline__ unsigned f2bf(float x) {   // RNE f32->bf16
    unsigned u = __float_as_uint(x);
    return (u + 0x7fffu + ((u >> 16) & 1u)) >> 16;
}
static __device__ __forceinline__ float bf2f(unsigned h) {
    return __uint_as_float(h << 16);
}
static __device__ __forceinline__ f32x4 mfma16(short8 a, short8 b, f32x4 c) {
    return __builtin_amdgcn_mfma_f32_16x16x32_bf16(a, b, c, 0, 0, 0);
}

__global__ __launch_bounds__(512)
void adj_bits_kernel(const float* __restrict__ adj, unsigned long long* __restrict__ bits)
{
    const int tid  = threadIdx.x;
    const int lane = tid & 63;
    const int w    = tid >> 6;
    const int g    = blockIdx.x * 8 + w;   // 0..4095
    const int row  = g >> 3;
    const int k    = g & 7;
    float v = adj[row * 512 + k * 64 + lane];
    unsigned long long m = __ballot(v > 0.f);
    if (lane == 0) bits[row * 8 + k] = m;
}

// ---------------- Phase 1: Wh = h@W -> WhT hi/lo (bf16), wh1, wh2 ----------
__global__ __launch_bounds__(256)
void gat_phase1(const float* __restrict__ h, const float* __restrict__ W,
                const float* __restrict__ a,
                unsigned short* __restrict__ WhT_hi,
                unsigned short* __restrict__ WhT_lo,
                float* __restrict__ wh1g, float* __restrict__ wh2g)
{
    __shared__ float sW[64 * 68];     // [k][o + pad]
    __shared__ float hT[64 * 68];     // [k][n_local + pad]; reused as Wh[n][o] tile

    const int tid  = threadIdx.x;
    const int lane = tid & 63;
    const int wv   = tid >> 6;        // 0..3
    const int bt   = blockIdx.x >> 2;
    const int q    = blockIdx.x & 3;
    const size_t base = (size_t)bt * 32768;

    const int o4 = (lane & 15) * 4;
    const int jq = lane >> 4;

    // stage W [k][o]: idx = k*64+o; lane-consecutive reads
    #pragma unroll
    for (int t = 0; t < 16; ++t) {
        int idx = t * 256 + tid;
        sW[(idx >> 6) * 68 + (idx & 63)] = W[idx];
    }
    const float4 a1v = *(const float4*)&a[o4];
    const float4 a2v = *(const float4*)&a[64 + o4];

    #pragma unroll 1
    for (int ci = 0; ci < 2; ++ci) {
        const int c  = q * 2 + ci;
        const int n0 = c * 64;
        __syncthreads();              // prev chunk's hT readers (convert) done
        #pragma unroll
        for (int t = 0; t < 16; ++t) {
            hT[lane * 68 + t * 4 + wv] = h[base + (size_t)(n0 + t * 4 + wv) * 64 + lane];
        }
        __syncthreads();

        float4 acc[16];
        #pragma unroll
        for (int r = 0; r < 16; ++r) acc[r] = make_float4(0.f, 0.f, 0.f, 0.f);

        #pragma unroll 4
        for (int l = 0; l < 16; ++l) {
            int k = l * 4 + jq;
            float4 w4 = *(const float4*)&sW[k * 68 + o4];
            const float* hrow = &hT[k * 68 + wv * 16];
            float4 ha = *(const float4*)&hrow[0];
            float4 hb = *(const float4*)&hrow[4];
            float4 hc = *(const float4*)&hrow[8];
            float4 hd = *(const float4*)&hrow[12];
            FMA4(acc[0],  ha.x, w4);
            FMA4(acc[1],  ha.y, w4);
            FMA4(acc[2],  ha.z, w4);
            FMA4(acc[3],  ha.w, w4);
            FMA4(acc[4],  hb.x, w4);
            FMA4(acc[5],  hb.y, w4);
            FMA4(acc[6],  hb.z, w4);
            FMA4(acc[7],  hb.w, w4);
            FMA4(acc[8],  hc.x, w4);
            FMA4(acc[9],  hc.y, w4);
            FMA4(acc[10], hc.z, w4);
            FMA4(acc[11], hc.w, w4);
            FMA4(acc[12], hd.x, w4);
            FMA4(acc[13], hd.y, w4);
            FMA4(acc[14], hd.z, w4);
            FMA4(acc[15], hd.w, w4);
        }

        __syncthreads();              // NEW: all waves done reading hT; reuse as Wh tile

        // reduce over jq; jq==0 lanes hold Wh[n][o4..o4+3] -> LDS tile + wh1/wh2
        #pragma unroll
        for (int r = 0; r < 16; ++r) {
            float4 v = acc[r];
            #pragma unroll
            for (int s = 16; s <= 32; s <<= 1) {
                v.x += __shfl_xor(v.x, s);
                v.y += __shfl_xor(v.y, s);
                v.z += __shfl_xor(v.z, s);
                v.w += __shfl_xor(v.w, s);
            }
            if (jq == 0) {
                const int nl = wv * 16 + r;        // local n in chunk
                *(float4*)&hT[nl * 68 + o4] = v;   // Wh[n][o] tile
                float t1 = v.x * a1v.x + v.y * a1v.y + v.z * a1v.z + v.w * a1v.w;
                float t2 = v.x * a2v.x + v.y * a2v.y + v.z * a2v.z + v.w * a2v.w;
                #pragma unroll
                for (int s = 1; s <= 8; s <<= 1) {   // lanes 0..15 all active
                    t1 += __shfl_xor(t1, s);
                    t2 += __shfl_xor(t2, s);
                }
                if (lane == 0) { wh1g[bt * 512 + n0 + nl] = t1; wh2g[bt * 512 + n0 + nl] = t2; }
            }
        }

        __syncthreads();              // NEW: Wh tile complete

        // transpose + bf16 hi/lo split: thread (o, nq) writes 16 consecutive j
        {
            const int o  = tid & 63;
            const int nq = tid >> 6;
            const size_t tb = ((size_t)bt * 64 + o) * 512 + (size_t)n0 + nq * 16;
            unsigned hi[8], lo[8];
            #pragma unroll
            for (int i2 = 0; i2 < 8; ++i2) {
                float v0 = hT[(nq * 16 + 2 * i2    ) * 68 + o];
                float v1 = hT[(nq * 16 + 2 * i2 + 1) * 68 + o];
                unsigned h0 = f2bf(v0), h1 = f2bf(v1);
                hi[i2] = h0 | (h1 << 16);
                unsigned l0 = f2bf(v0 - bf2f(h0));
                unsigned l1 = f2bf(v1 - bf2f(h1));
                lo[i2] = l0 | (l1 << 16);
            }
            *(uint4*)&WhT_hi[tb]     = make_uint4(hi[0], hi[1], hi[2], hi[3]);
            *(uint4*)&WhT_hi[tb + 8] = make_uint4(hi[4], hi[5], hi[6], hi[7]);
            *(uint4*)&WhT_lo[tb]     = make_uint4(lo[0], lo[1], lo[2], lo[3]);
            *(uint4*)&WhT_lo[tb + 8] = make_uint4(lo[4], lo[5], lo[6], lo[7]);
        }
    }
}

// ---------------- wh2 max per bt (softmax stability bound) ----------------
__global__ __launch_bounds__(64)
void wh2_max_kernel(const float* __restrict__ wh2g, float* __restrict__ M2g)
{
    const int bt   = blockIdx.x;
    const int lane = threadIdx.x;
    float m = -3.4e38f;
    #pragma unroll
    for (int k = 0; k < 8; ++k) m = fmaxf(m, wh2g[bt * 512 + k * 64 + lane]);
    #pragma unroll
    for (int s = 32; s > 0; s >>= 1) m = fmaxf(m, __shfl_xor(m, s));
    if (lane == 0) M2g[bt] = m;
}

// ---------------- Phase 2: MFMA softmax-matmul + ELU (no LDS) --------------
// Block = (bt, 128-row slab); wave = 32 rows (2 m-tiles) x 64 o (4 o-tiles).
// K-loop over j in steps of 32. Denominator via MFMA against ones-frag.
__global__ __launch_bounds__(256)
void gat_phase2_mfma(const unsigned short* __restrict__ WhT_hi,
                     const unsigned short* __restrict__ WhT_lo,
                     const float* __restrict__ wh1g,
                     const float* __restrict__ wh2g,
                     const float* __restrict__ M2g,
                     const unsigned long long* __restrict__ bits,
                     float* __restrict__ out)
{
    const int bid = blockIdx.x;
    const int swz = (bid & 7) * 96 + (bid >> 3);  // XCD-chunked: a bt's 4 blocks share an L2
    const int bt  = swz >> 2;
    const int blk = swz & 3;

    const int tid  = threadIdx.x;
    const int lane = tid & 63;
    const int wv   = tid >> 6;
    const int col  = lane & 15;
    const int g    = lane >> 4;

    const int ibase = blk * 128 + wv * 32;
    const int row0  = ibase + col;        // A-frag row, m-tile 0
    const int row1  = row0 + 16;          // m-tile 1

    const float M2   = M2g[bt];
    const float wh10 = wh1g[bt * 512 + row0];
    const float wh11 = wh1g[bt * 512 + row1];
    const float b0   = fmaxf(0.f, wh10 + M2);
    const float b1   = fmaxf(0.f, wh11 + M2);

    short8 ones;
    #pragma unroll
    for (int r = 0; r < 8; ++r) ones[r] = (short)0x3F80;   // bf16 1.0

    f32x4 acc[2][4];
    f32x4 sacc[2];
    #pragma unroll
    for (int it = 0; it < 2; ++it) {
        sacc[it] = (f32x4){0.f, 0.f, 0.f, 0.f};
        #pragma unroll
        for (int ot = 0; ot < 4; ++ot) acc[it][ot] = (f32x4){0.f, 0.f, 0.f, 0.f};
    }

    const float* w2base = &wh2g[bt * 512];
    const size_t whtb   = (size_t)bt * 64 * 512;

    #pragma unroll 1
    for (int k0 = 0; k0 < 512; k0 += 32) {
        // ---- B frags: WhT[col][k0+8g .. +7]; 16 full 64B lines per instr
        short8 bh[4], bl[4];
        #pragma unroll
        for (int ot = 0; ot < 4; ++ot) {
            const size_t off = whtb + (size_t)(ot * 16 + col) * 512 + (size_t)(k0 + 8 * g);
            U16x8 th; th.v = *(const uint4*)&WhT_hi[off]; bh[ot] = th.s;
            U16x8 tl; tl.v = *(const uint4*)&WhT_lo[off]; bl[ot] = tl.s;
        }

        // ---- wh2 for this lane's 8 j (broadcast within g-group, L1-served)
        const float4 w2a = *(const float4*)&w2base[k0 + 8 * g];
        const float4 w2b = *(const float4*)&w2base[k0 + 8 * g + 4];
        const float w2[8] = {w2a.x, w2a.y, w2a.z, w2a.w, w2b.x, w2b.y, w2b.z, w2b.w};

        // ---- adjacency byte for this lane's 8 j
        const int wi = k0 >> 6;
        const int sh = (k0 & 32) + 8 * g;
        const unsigned m0 = (unsigned)(bits[(size_t)row0 * 8 + wi] >> sh) & 0xffu;
        const unsigned m1 = (unsigned)(bits[(size_t)row1 * 8 + wi] >> sh) & 0xffu;

        // ---- p in A-frag layout, split hi/lo, packed pairwise
        unsigned h0w[4], l0w[4], h1w[4], l1w[4];
        #pragma unroll
        for (int pr = 0; pr < 4; ++pr) {
            const int r0 = 2 * pr, r1 = 2 * pr + 1;

            float ea = wh10 + w2[r0];
            ea = fmaxf(ea, LRELU_ALPHA * ea);
            float pa = ((m0 >> r0) & 1u) ? __expf(ea - b0) : 0.f;
            float eb = wh10 + w2[r1];
            eb = fmaxf(eb, LRELU_ALPHA * eb);
            float pb = ((m0 >> r1) & 1u) ? __expf(eb - b0) : 0.f;
            unsigned ha = f2bf(pa), hb = f2bf(pb);
            h0w[pr] = ha | (hb << 16);
            l0w[pr] = f2bf(pa - bf2f(ha)) | (f2bf(pb - bf2f(hb)) << 16);

            float ec = wh11 + w2[r0];
            ec = fmaxf(ec, LRELU_ALPHA * ec);
            float pc = ((m1 >> r0) & 1u) ? __expf(ec - b1) : 0.f;
            float ed = wh11 + w2[r1];
            ed = fmaxf(ed, LRELU_ALPHA * ed);
            float pd = ((m1 >> r1) & 1u) ? __expf(ed - b1) : 0.f;
            unsigned hc = f2bf(pc), hd = f2bf(pd);
            h1w[pr] = hc | (hd << 16);
            l1w[pr] = f2bf(pc - bf2f(hc)) | (f2bf(pd - bf2f(hd)) << 16);
        }
        U16x8 A0h; A0h.v = make_uint4(h0w[0], h0w[1], h0w[2], h0w[3]);
        U16x8 A0l; A0l.v = make_uint4(l0w[0], l0w[1], l0w[2], l0w[3]);
        U16x8 A1h; A1h.v = make_uint4(h1w[0], h1w[1], h1w[2], h1w[3]);
        U16x8 A1l; A1l.v = make_uint4(l1w[0], l1w[1], l1w[2], l1w[3]);

        // ---- denominator: s[row] accumulates in D layout (every col)
        sacc[0] = mfma16(A0h.s, ones, sacc[0]);
        sacc[0] = mfma16(A0l.s, ones, sacc[0]);
        sacc[1] = mfma16(A1h.s, ones, sacc[1]);
        sacc[1] = mfma16(A1l.s, ones, sacc[1]);

        // ---- numerator: 3-product split-bf16
        #pragma unroll
        for (int ot = 0; ot < 4; ++ot) {
            acc[0][ot] = mfma16(A0h.s, bh[ot], acc[0][ot]);
            acc[0][ot] = mfma16(A0l.s, bh[ot], acc[0][ot]);
            acc[0][ot] = mfma16(A0h.s, bl[ot], acc[0][ot]);
            acc[1][ot] = mfma16(A1h.s, bh[ot], acc[1][ot]);
            acc[1][ot] = mfma16(A1l.s, bh[ot], acc[1][ot]);
            acc[1][ot] = mfma16(A1h.s, bl[ot], acc[1][ot]);
        }
    }

    // ---- epilogue: divide by s (same D layout), ELU, coalesced stores
    const size_t ob = (size_t)bt * 32768;
    #pragma unroll
    for (int it = 0; it < 2; ++it) {
        float inv[4];
        #pragma unroll
        for (int r = 0; r < 4; ++r) inv[r] = 1.f / sacc[it][r];
        #pragma unroll
        for (int ot = 0; ot < 4; ++ot) {
            #pragma unroll
            for (int r = 0; r < 4; ++r) {
                float v = acc[it][ot][r] * inv[r];
                v = (v > 0.f) ? v : __expf(v) - 1.f;
                const int rowi = ibase + it * 16 + g * 4 + r;
                out[ob + (size_t)rowi * 64 + ot * 16 + col] = v;
            }
        }
    }
}

extern "C" void kernel_launch(void* const* d_in, const int* in_sizes, int n_in,
                              void* d_out, int out_size, void* d_ws, size_t ws_size,
                              hipStream_t stream)
{
    const float* h   = (const float*)d_in[0];   // (16,12,512,64)
    const float* adj = (const float*)d_in[1];   // (512,512)
    const float* W   = (const float*)d_in[2];   // (64,64)
    const float* a   = (const float*)d_in[3];   // (128,1)
    float* out = (float*)d_out;                 // (16,12,512,64)

    // workspace layout (25,985,792 B — identical total to round 8)
    unsigned long long* bits = (unsigned long long*)d_ws;                   // 32 KB
    unsigned short* WhT_hi = (unsigned short*)((char*)d_ws + 32768);        // 12.58 MB
    unsigned short* WhT_lo = WhT_hi + (size_t)192 * 64 * 512;               // 12.58 MB
    float* wh1g = (float*)(WhT_lo + (size_t)192 * 64 * 512);                // 384 KB
    float* wh2g = wh1g + (size_t)192 * 512;                                 // 384 KB
    float* M2g  = wh2g + (size_t)192 * 512;                                 // 768 B

    adj_bits_kernel<<<512, 512, 0, stream>>>(adj, bits);
    gat_phase1<<<768, 256, 0, stream>>>(h, W, a, WhT_hi, WhT_lo, wh1g, wh2g);
    wh2_max_kernel<<<192, 64, 0, stream>>>(wh2g, M2g);
    gat_phase2_mfma<<<768, 256, 0, stream>>>(WhT_hi, WhT_lo, wh1g, wh2g, M2g, bits, out);
}